// Round 11
// baseline (131.518 us; speedup 1.0000x reference)
//
#include <hip/hip_runtime.h>
#include <hip/hip_bf16.h>
#include <stdint.h>

#define NB   8
#define NN   2048
#define NE   16384
#define OBS  128
#define HID  256
#define OUTF 1024
#define BCAP 64   // per-node bucket capacity (mean deg 8, sigma 2.8)

using bfrag = __attribute__((ext_vector_type(8))) short;
using ffrag = __attribute__((ext_vector_type(4))) float;

__device__ __forceinline__ short f2bf(float f) {
    __hip_bfloat16 h = __float2bfloat16(f);
    return __builtin_bit_cast(short, h);
}
__device__ __forceinline__ unsigned packbf(float a, float b) {
    return ((unsigned)(unsigned short)f2bf(b) << 16) | (unsigned)(unsigned short)f2bf(a);
}
__device__ __forceinline__ void gload_lds16(const void* g, void* l) {
    __builtin_amdgcn_global_load_lds(
        (const __attribute__((address_space(1))) unsigned int*)g,
        (__attribute__((address_space(3))) unsigned int*)l, 16, 0, 0);
}

// ------- bucket scatter + weight transposes (cnt pre-zeroed by memset) -------
// grid 1024x256 = 262144 threads: 1 W1t elem each; idx<131072 also scatters an
// edge; idx<32768 also does a W0t elem. W reads are linear/coalesced.
__global__ __launch_bounds__(256) void k_bucket(const int* __restrict__ edges,
                                                const float* __restrict__ W0,
                                                const float* __restrict__ W1,
                                                int* __restrict__ cnt,
                                                int* __restrict__ bucket,
                                                short* __restrict__ W0t,
                                                short* __restrict__ W1t) {
    int idx = blockIdx.x * 256 + threadIdx.x;
    {   // W1t [OUTF][HID] <- W1 [HID][OUTF], read-coalesced
        int k = idx >> 10, n = idx & 1023;
        W1t[n * HID + k] = f2bf(W1[idx]);
    }
    if (idx < OBS * HID) {  // W0t [HID][OBS] <- W0 [OBS][HID]
        int k = idx >> 8, n = idx & 255;
        W0t[n * OBS + k] = f2bf(W0[idx]);
    }
    if (idx < NB * NE) {
        int b = idx >> 14, e = idx & (NE - 1);
        int src = edges[(size_t)b * 2 * NE + e];
        int dst = edges[(size_t)b * 2 * NE + NE + e];
        int pos = atomicAdd(&cnt[b * NN + dst], 1);
        if (pos < BCAP) bucket[((size_t)b * NN + dst) * BCAP + pos] = src;
    }
}

// ------- fused layer 1: agg (S.nodes -> LDS A-tile, swizzled) + GEMM -------
// 256 blocks (128 rtiles x 2 ctiles), 256 thr. LDS: A 32KB (XOR-swizzled
// [128][128] bf16) + B dbuf 2x4KB. x1 = relu((S.nodes) @ W0t^T + b0), bf16.
__global__ __launch_bounds__(256, 3) void gemm1_fused(const float* __restrict__ nodes,
                                                      const int* __restrict__ cnt,
                                                      const int* __restrict__ bucket,
                                                      const short* __restrict__ W0t,
                                                      const float* __restrict__ b0,
                                                      short* __restrict__ x1) {
    constexpr int K = OBS, N = HID, BK = 32, NC = N / 128;
    __shared__ short Asw[128 * 128];      // 32KB, swizzled
    __shared__ short Bs[2][128 * BK];     // 2x8KB
    const int h = blockIdx.x;
    const int rtile = (h & 7) + 8 * (h / (8 * NC));
    const int ctile = (h >> 3) % NC;
    const int tid = threadIdx.x;
    const int lane = tid & 63, wid = tid >> 6;
    const int wr = wid >> 1, wc = wid & 1;
    const int lrow = lane & 15, lk = (lane >> 4) * 8;
    const int row0 = rtile * 128;
    const int b = row0 >> 11;             // whole block within one graph
    const int* cb = cnt + b * NN;
    const float* xb = nodes + (size_t)b * NN * OBS;

    // ---- agg phase: wave w computes rows w*32 .. w*32+31 ----
    for (int it = 0; it < 32; ++it) {
        const int row = wid * 32 + it;
        const int i = (row0 + row) & (NN - 1);
        const int deg = cb[i];
        const int degc = deg < BCAP ? deg : BCAP;
        const float di = rsqrtf((float)(deg + 1));
        int s_t = 0;
        float dv_t = 0.f;
        if (lane < degc) {
            s_t = bucket[((size_t)b * NN + i) * BCAP + lane];
            dv_t = rsqrtf((float)(cb[s_t] + 1));
        }
        float2 v = *(const float2*)&xb[(size_t)i * OBS + lane * 2];
        float ax = di * di * v.x, ay = di * di * v.y;
        float bx = 0.f, by = 0.f;
        int e = 0;
        for (; e + 2 <= degc; e += 2) {
            int sA = __shfl(s_t, e), sB = __shfl(s_t, e + 1);
            float wA = di * __shfl(dv_t, e), wB = di * __shfl(dv_t, e + 1);
            float2 uA = *(const float2*)&xb[(size_t)sA * OBS + lane * 2];
            float2 uB = *(const float2*)&xb[(size_t)sB * OBS + lane * 2];
            ax = fmaf(wA, uA.x, ax); ay = fmaf(wA, uA.y, ay);
            bx = fmaf(wB, uB.x, bx); by = fmaf(wB, uB.y, by);
        }
        if (e < degc) {
            int s = __shfl(s_t, e);
            float w = di * __shfl(dv_t, e);
            float2 u = *(const float2*)&xb[(size_t)s * OBS + lane * 2];
            ax = fmaf(w, u.x, ax);
            ay = fmaf(w, u.y, ay);
        }
        // swizzled store: byte = row*256 + ((lane*4) ^ ((row&7)<<4))
        int byte = row * 256 + ((lane * 4) ^ ((row & 7) << 4));
        *(unsigned*)((char*)Asw + byte) = packbf(ax + bx, ay + by);
    }

    // ---- GEMM phase: A from LDS (swizzled), B dbuf staged ----
    const short* gB = W0t + (size_t)(ctile * 128) * K;
    auto stageB = [&](int buf, int kt) {
#pragma unroll
        for (int c = 0; c < 2; ++c) {
            int off = c * 4096 + tid * 16;
            int rw = off >> 6, kb = (off & 63) >> 1;  // 64B per B row
            gload_lds16(gB + (size_t)rw * K + kt + kb, (char*)&Bs[buf][0] + off);
        }
    };
    ffrag acc[4][4] = {};
    stageB(0, 0);
    __syncthreads();  // covers agg writes + B buf0
    const int NT = K / BK;  // 4
    int cur = 0;
    for (int kt = 0; kt < NT; ++kt) {
        if (kt + 1 < NT) stageB(cur ^ 1, (kt + 1) * BK);
        bfrag a[4], bf[4];
#pragma unroll
        for (int m = 0; m < 4; ++m) {
            int rowA = wr * 64 + m * 16 + lrow;
            int abyte = rowA * 256 + ((kt * 64 + lk * 2) ^ ((rowA & 7) << 4));
            a[m] = *(const bfrag*)((const char*)Asw + abyte);
        }
#pragma unroll
        for (int n = 0; n < 4; ++n)
            bf[n] = *(const bfrag*)&Bs[cur][(wc * 64 + n * 16 + lrow) * BK + lk];
#pragma unroll
        for (int m = 0; m < 4; ++m)
#pragma unroll
            for (int n = 0; n < 4; ++n)
                acc[m][n] = __builtin_amdgcn_mfma_f32_16x16x32_bf16(a[m], bf[n], acc[m][n], 0, 0, 0);
        __syncthreads();
        cur ^= 1;
    }

    const int orow = row0 + wr * 64 + (lane >> 4) * 4;
    const int ocol = ctile * 128 + wc * 64 + lrow;
#pragma unroll
    for (int n = 0; n < 4; ++n) {
        float bv = b0[ocol + n * 16];
#pragma unroll
        for (int m = 0; m < 4; ++m)
#pragma unroll
            for (int r = 0; r < 4; ++r) {
                float v = fmaxf(acc[m][n][r] + bv, 0.f);
                x1[(size_t)(orow + m * 16 + r) * N + ocol + n * 16] = f2bf(v);
            }
    }
}

// ---------------- z1 = S . x1 (bf16, F=256; wave per node, 4x MLP) ----------------
__global__ __launch_bounds__(256) void k_agg1(const short* __restrict__ x1,
                                              const int* __restrict__ cnt,
                                              const int* __restrict__ bucket,
                                              unsigned* __restrict__ z1) {
    const int b = blockIdx.y, t = threadIdx.x;
    const int i = blockIdx.x * 4 + (t >> 6);
    const int l = t & 63;
    const int* cb = cnt + b * NN;
    const int deg = cb[i];
    const int degc = deg < BCAP ? deg : BCAP;
    const float di = rsqrtf((float)(deg + 1));
    int s_t = 0;
    float dv_t = 0.f;
    if (l < degc) {
        s_t = bucket[((size_t)b * NN + i) * BCAP + l];
        dv_t = rsqrtf((float)(cb[s_t] + 1));
    }
    const short* xb = x1 + (size_t)b * NN * HID;
    uint2 raw = *(const uint2*)&xb[(size_t)i * HID + l * 4];
    const float di2 = di * di;
    float a0 = di2 * __uint_as_float(raw.x << 16);
    float a1 = di2 * __uint_as_float(raw.x & 0xffff0000u);
    float a2 = di2 * __uint_as_float(raw.y << 16);
    float a3 = di2 * __uint_as_float(raw.y & 0xffff0000u);
    float c0 = 0.f, c1 = 0.f, c2 = 0.f, c3 = 0.f;
    int e = 0;
    for (; e + 4 <= degc; e += 4) {
        int s0 = __shfl(s_t, e),     s1 = __shfl(s_t, e + 1);
        int s2 = __shfl(s_t, e + 2), s3 = __shfl(s_t, e + 3);
        float w0 = di * __shfl(dv_t, e),     w1 = di * __shfl(dv_t, e + 1);
        float w2 = di * __shfl(dv_t, e + 2), w3 = di * __shfl(dv_t, e + 3);
        uint2 u0 = *(const uint2*)&xb[(size_t)s0 * HID + l * 4];
        uint2 u1 = *(const uint2*)&xb[(size_t)s1 * HID + l * 4];
        uint2 u2 = *(const uint2*)&xb[(size_t)s2 * HID + l * 4];
        uint2 u3 = *(const uint2*)&xb[(size_t)s3 * HID + l * 4];
        a0 = fmaf(w0, __uint_as_float(u0.x << 16), a0);
        a1 = fmaf(w0, __uint_as_float(u0.x & 0xffff0000u), a1);
        a2 = fmaf(w0, __uint_as_float(u0.y << 16), a2);
        a3 = fmaf(w0, __uint_as_float(u0.y & 0xffff0000u), a3);
        c0 = fmaf(w1, __uint_as_float(u1.x << 16), c0);
        c1 = fmaf(w1, __uint_as_float(u1.x & 0xffff0000u), c1);
        c2 = fmaf(w1, __uint_as_float(u1.y << 16), c2);
        c3 = fmaf(w1, __uint_as_float(u1.y & 0xffff0000u), c3);
        a0 = fmaf(w2, __uint_as_float(u2.x << 16), a0);
        a1 = fmaf(w2, __uint_as_float(u2.x & 0xffff0000u), a1);
        a2 = fmaf(w2, __uint_as_float(u2.y << 16), a2);
        a3 = fmaf(w2, __uint_as_float(u2.y & 0xffff0000u), a3);
        c0 = fmaf(w3, __uint_as_float(u3.x << 16), c0);
        c1 = fmaf(w3, __uint_as_float(u3.x & 0xffff0000u), c1);
        c2 = fmaf(w3, __uint_as_float(u3.y << 16), c2);
        c3 = fmaf(w3, __uint_as_float(u3.y & 0xffff0000u), c3);
    }
    for (; e < degc; ++e) {
        int s = __shfl(s_t, e);
        float w = di * __shfl(dv_t, e);
        uint2 u = *(const uint2*)&xb[(size_t)s * HID + l * 4];
        a0 = fmaf(w, __uint_as_float(u.x << 16), a0);
        a1 = fmaf(w, __uint_as_float(u.x & 0xffff0000u), a1);
        a2 = fmaf(w, __uint_as_float(u.y << 16), a2);
        a3 = fmaf(w, __uint_as_float(u.y & 0xffff0000u), a3);
    }
    a0 += c0; a1 += c1; a2 += c2; a3 += c3;
    uint2 o;
    o.x = packbf(a0, a1);
    o.y = packbf(a2, a3);
    *(uint2*)&z1[(((size_t)b * NN + i) * HID + l * 4) >> 1] = o;
}

// ---------------- gemm2: 128x256 tile, BK=32, 512 thr (8 waves 2x4) ----------------
template <int K>
__global__ __launch_bounds__(512, 4) void gemm_wide(const short* __restrict__ A,
                                                    const short* __restrict__ Bt,
                                                    const float* __restrict__ bias,
                                                    float* __restrict__ C) {
    constexpr int N = OUTF, BK = 32, BM = 128, BN = 256;
    __shared__ short lds[2][(BM + BN) * BK];
    const int h = blockIdx.x;
    const int rtile = (h & 7) + 8 * (h >> 5);
    const int ctile = (h >> 3) & 3;
    const int tid = threadIdx.x;
    const int lane = tid & 63, wid = tid >> 6;
    const int wr = wid >> 2, wc = wid & 3;
    const int lrow = lane & 15, lk = (lane >> 4) * 8;
    const short* gA = A + (size_t)(rtile * BM) * K;
    const short* gB = Bt + (size_t)(ctile * BN) * K;

    auto stage = [&](int buf, int kt) {
        {
            int off = tid * 16;
            int row = off >> 6, kb = (off & 63) >> 1;
            gload_lds16(gA + (size_t)row * K + kt + kb, (char*)&lds[buf][0] + off);
        }
#pragma unroll
        for (int c = 0; c < 2; ++c) {
            int off = c * 8192 + tid * 16;
            int row = off >> 6, kb = (off & 63) >> 1;
            gload_lds16(gB + (size_t)row * K + kt + kb, (char*)&lds[buf][BM * BK] + off);
        }
    };

    ffrag acc[4][4] = {};
    stage(0, 0);
    __syncthreads();
    const int NT = K / BK;
    int cur = 0;
    for (int kt = 0; kt < NT; ++kt) {
        if (kt + 1 < NT) stage(cur ^ 1, (kt + 1) * BK);
        const short* As = &lds[cur][0];
        const short* Bs = &lds[cur][BM * BK];
        bfrag a[4], b[4];
#pragma unroll
        for (int m = 0; m < 4; ++m)
            a[m] = *(const bfrag*)&As[(wr * 64 + m * 16 + lrow) * BK + lk];
#pragma unroll
        for (int n = 0; n < 4; ++n)
            b[n] = *(const bfrag*)&Bs[(wc * 64 + n * 16 + lrow) * BK + lk];
#pragma unroll
        for (int m = 0; m < 4; ++m)
#pragma unroll
            for (int n = 0; n < 4; ++n)
                acc[m][n] = __builtin_amdgcn_mfma_f32_16x16x32_bf16(a[m], b[n], acc[m][n], 0, 0, 0);
        __syncthreads();
        cur ^= 1;
    }

    const int orow = rtile * BM + wr * 64 + (lane >> 4) * 4;
    const int ocol = ctile * BN + wc * 64 + lrow;
#pragma unroll
    for (int n = 0; n < 4; ++n) {
        float bv = bias[ocol + n * 16];
#pragma unroll
        for (int m = 0; m < 4; ++m)
#pragma unroll
            for (int r = 0; r < 4; ++r) {
                float v = fmaxf(acc[m][n][r] + bv, 0.f);
                C[(size_t)(orow + m * 16 + r) * N + ocol + n * 16] = v;
            }
    }
}

extern "C" void kernel_launch(void* const* d_in, const int* in_sizes, int n_in,
                              void* d_out, int out_size, void* d_ws, size_t ws_size,
                              hipStream_t stream) {
    const float* nodes = (const float*)d_in[0];
    const int*   edges = (const int*)d_in[1];
    const float* W0    = (const float*)d_in[2];
    const float* b0    = (const float*)d_in[3];
    const float* W1    = (const float*)d_in[4];
    const float* b1    = (const float*)d_in[5];
    float* out = (float*)d_out;

    char* ws = (char*)d_ws;
    size_t off = 0;
    auto alloc = [&](size_t bytes) -> char* {
        char* p = ws + off;
        off = (off + bytes + 255) & ~(size_t)255;
        return p;
    };
    int*   cnt    = (int*)alloc((size_t)NB * NN * 4);
    int*   bucket = (int*)alloc((size_t)NB * NN * BCAP * 4);   // 4 MB
    short* W0t    = (short*)alloc((size_t)HID * OBS * 2);
    short* W1t    = (short*)alloc((size_t)OUTF * HID * 2);
    short* x1     = (short*)alloc((size_t)NB * NN * HID * 2);  // 8 MB
    short* z1     = (short*)alloc((size_t)NB * NN * HID * 2);  // 8 MB

    // 1: zero cnt (64 KB async fill node)
    hipMemsetAsync(cnt, 0, (size_t)NB * NN * 4, stream);
    // 2: edge bucket scatter + weight transposes
    k_bucket<<<(HID * OUTF) / 256, 256, 0, stream>>>(edges, W0, W1, cnt, bucket, W0t, W1t);
    // 3: fused layer 1 (agg0 in-LDS + GEMM): x1 = relu((S.nodes)@W0 + b0)
    gemm1_fused<<<(NB * NN / 128) * (HID / 128), 256, 0, stream>>>(nodes, cnt, bucket, W0t, b0, x1);
    // 4: z1 = S.x1
    k_agg1<<<dim3(NN / 4, NB), 256, 0, stream>>>(x1, cnt, bucket, (unsigned*)z1);
    // 5: out = relu(z1 @ W1 + b1)
    gemm_wide<HID><<<(NB * NN / 128) * (OUTF / 256), 512, 0, stream>>>(z1, W1t, b1, out);
}

// Round 12
// 69.480 us; speedup vs baseline: 1.8929x; 1.8929x over previous
//
#include <hip/hip_runtime.h>
#include <hip/hip_bf16.h>
#include <stdint.h>

#define NB   8
#define NN   2048
#define NE   16384
#define OBS  128
#define HID  256
#define OUTF 1024
#define BCAP 64   // per-node bucket capacity (mean deg 8, sigma 2.8)

using bfrag = __attribute__((ext_vector_type(8))) short;
using ffrag = __attribute__((ext_vector_type(4))) float;

__device__ __forceinline__ short f2bf(float f) {
    __hip_bfloat16 h = __float2bfloat16(f);
    return __builtin_bit_cast(short, h);
}
__device__ __forceinline__ unsigned packbf(float a, float b) {
    return ((unsigned)(unsigned short)f2bf(b) << 16) | (unsigned)(unsigned short)f2bf(a);
}
__device__ __forceinline__ void gload_lds16(const void* g, void* l) {
    __builtin_amdgcn_global_load_lds(
        (const __attribute__((address_space(1))) unsigned int*)g,
        (__attribute__((address_space(3))) unsigned int*)l, 16, 0, 0);
}

// ------- bucket scatter + weight transposes (cnt pre-zeroed by memset) -------
// grid 1024x256 = 262144 threads: 1 W1t elem each (read-coalesced); idx<131072
// also scatters an edge; idx<32768 also does a W0t elem.
__global__ __launch_bounds__(256) void k_bucket(const int* __restrict__ edges,
                                                const float* __restrict__ W0,
                                                const float* __restrict__ W1,
                                                int* __restrict__ cnt,
                                                int* __restrict__ bucket,
                                                short* __restrict__ W0t,
                                                short* __restrict__ W1t) {
    int idx = blockIdx.x * 256 + threadIdx.x;
    {   // W1t [OUTF][HID] <- W1 [HID][OUTF]
        int k = idx >> 10, n = idx & 1023;
        W1t[n * HID + k] = f2bf(W1[idx]);
    }
    if (idx < OBS * HID) {  // W0t [HID][OBS] <- W0 [OBS][HID]
        int k = idx >> 8, n = idx & 255;
        W0t[n * OBS + k] = f2bf(W0[idx]);
    }
    if (idx < NB * NE) {
        int b = idx >> 14, e = idx & (NE - 1);
        int src = edges[(size_t)b * 2 * NE + e];
        int dst = edges[(size_t)b * 2 * NE + NE + e];
        int pos = atomicAdd(&cnt[b * NN + dst], 1);
        if (pos < BCAP) bucket[((size_t)b * NN + dst) * BCAP + pos] = src;
    }
}

// ---------------- pre-GEMM aggregation z = S.x (wave per node, 4x MLP) ----------------
// z0 = S . nodes  (f32 in -> bf16 out, F=128; 2 f32/lane)
__global__ __launch_bounds__(256) void k_agg0(const float* __restrict__ nodes,
                                              const int* __restrict__ cnt,
                                              const int* __restrict__ bucket,
                                              unsigned* __restrict__ z0) {
    const int b = blockIdx.y, t = threadIdx.x;
    const int i = blockIdx.x * 4 + (t >> 6);
    const int l = t & 63;
    const int* cb = cnt + b * NN;
    const int deg = cb[i];
    const int degc = deg < BCAP ? deg : BCAP;
    const float di = rsqrtf((float)(deg + 1));
    int s_t = 0;
    float dv_t = 0.f;
    if (l < degc) {
        s_t = bucket[((size_t)b * NN + i) * BCAP + l];
        dv_t = rsqrtf((float)(cb[s_t] + 1));
    }
    const float* xb = nodes + (size_t)b * NN * OBS;
    float2 v = *(const float2*)&xb[(size_t)i * OBS + l * 2];
    float ax = di * di * v.x, ay = di * di * v.y;
    float bx = 0.f, by = 0.f;
    int e = 0;
    for (; e + 4 <= degc; e += 4) {
        int s0 = __shfl(s_t, e),     s1 = __shfl(s_t, e + 1);
        int s2 = __shfl(s_t, e + 2), s3 = __shfl(s_t, e + 3);
        float w0 = di * __shfl(dv_t, e),     w1 = di * __shfl(dv_t, e + 1);
        float w2 = di * __shfl(dv_t, e + 2), w3 = di * __shfl(dv_t, e + 3);
        float2 u0 = *(const float2*)&xb[(size_t)s0 * OBS + l * 2];
        float2 u1 = *(const float2*)&xb[(size_t)s1 * OBS + l * 2];
        float2 u2 = *(const float2*)&xb[(size_t)s2 * OBS + l * 2];
        float2 u3 = *(const float2*)&xb[(size_t)s3 * OBS + l * 2];
        ax = fmaf(w0, u0.x, ax); ay = fmaf(w0, u0.y, ay);
        bx = fmaf(w1, u1.x, bx); by = fmaf(w1, u1.y, by);
        ax = fmaf(w2, u2.x, ax); ay = fmaf(w2, u2.y, ay);
        bx = fmaf(w3, u3.x, bx); by = fmaf(w3, u3.y, by);
    }
    for (; e < degc; ++e) {
        int s = __shfl(s_t, e);
        float w = di * __shfl(dv_t, e);
        float2 u = *(const float2*)&xb[(size_t)s * OBS + l * 2];
        ax = fmaf(w, u.x, ax);
        ay = fmaf(w, u.y, ay);
    }
    ax += bx;
    ay += by;
    z0[(((size_t)b * NN + i) * OBS + l * 2) >> 1] = packbf(ax, ay);
}

// z1 = S . x1  (bf16 in -> bf16 out, F=256; 4 bf16/lane)
__global__ __launch_bounds__(256) void k_agg1(const short* __restrict__ x1,
                                              const int* __restrict__ cnt,
                                              const int* __restrict__ bucket,
                                              unsigned* __restrict__ z1) {
    const int b = blockIdx.y, t = threadIdx.x;
    const int i = blockIdx.x * 4 + (t >> 6);
    const int l = t & 63;
    const int* cb = cnt + b * NN;
    const int deg = cb[i];
    const int degc = deg < BCAP ? deg : BCAP;
    const float di = rsqrtf((float)(deg + 1));
    int s_t = 0;
    float dv_t = 0.f;
    if (l < degc) {
        s_t = bucket[((size_t)b * NN + i) * BCAP + l];
        dv_t = rsqrtf((float)(cb[s_t] + 1));
    }
    const short* xb = x1 + (size_t)b * NN * HID;
    uint2 raw = *(const uint2*)&xb[(size_t)i * HID + l * 4];
    const float di2 = di * di;
    float a0 = di2 * __uint_as_float(raw.x << 16);
    float a1 = di2 * __uint_as_float(raw.x & 0xffff0000u);
    float a2 = di2 * __uint_as_float(raw.y << 16);
    float a3 = di2 * __uint_as_float(raw.y & 0xffff0000u);
    float c0 = 0.f, c1 = 0.f, c2 = 0.f, c3 = 0.f;
    int e = 0;
    for (; e + 4 <= degc; e += 4) {
        int s0 = __shfl(s_t, e),     s1 = __shfl(s_t, e + 1);
        int s2 = __shfl(s_t, e + 2), s3 = __shfl(s_t, e + 3);
        float w0 = di * __shfl(dv_t, e),     w1 = di * __shfl(dv_t, e + 1);
        float w2 = di * __shfl(dv_t, e + 2), w3 = di * __shfl(dv_t, e + 3);
        uint2 u0 = *(const uint2*)&xb[(size_t)s0 * HID + l * 4];
        uint2 u1 = *(const uint2*)&xb[(size_t)s1 * HID + l * 4];
        uint2 u2 = *(const uint2*)&xb[(size_t)s2 * HID + l * 4];
        uint2 u3 = *(const uint2*)&xb[(size_t)s3 * HID + l * 4];
        a0 = fmaf(w0, __uint_as_float(u0.x << 16), a0);
        a1 = fmaf(w0, __uint_as_float(u0.x & 0xffff0000u), a1);
        a2 = fmaf(w0, __uint_as_float(u0.y << 16), a2);
        a3 = fmaf(w0, __uint_as_float(u0.y & 0xffff0000u), a3);
        c0 = fmaf(w1, __uint_as_float(u1.x << 16), c0);
        c1 = fmaf(w1, __uint_as_float(u1.x & 0xffff0000u), c1);
        c2 = fmaf(w1, __uint_as_float(u1.y << 16), c2);
        c3 = fmaf(w1, __uint_as_float(u1.y & 0xffff0000u), c3);
        a0 = fmaf(w2, __uint_as_float(u2.x << 16), a0);
        a1 = fmaf(w2, __uint_as_float(u2.x & 0xffff0000u), a1);
        a2 = fmaf(w2, __uint_as_float(u2.y << 16), a2);
        a3 = fmaf(w2, __uint_as_float(u2.y & 0xffff0000u), a3);
        c0 = fmaf(w3, __uint_as_float(u3.x << 16), c0);
        c1 = fmaf(w3, __uint_as_float(u3.x & 0xffff0000u), c1);
        c2 = fmaf(w3, __uint_as_float(u3.y << 16), c2);
        c3 = fmaf(w3, __uint_as_float(u3.y & 0xffff0000u), c3);
    }
    for (; e < degc; ++e) {
        int s = __shfl(s_t, e);
        float w = di * __shfl(dv_t, e);
        uint2 u = *(const uint2*)&xb[(size_t)s * HID + l * 4];
        a0 = fmaf(w, __uint_as_float(u.x << 16), a0);
        a1 = fmaf(w, __uint_as_float(u.x & 0xffff0000u), a1);
        a2 = fmaf(w, __uint_as_float(u.y << 16), a2);
        a3 = fmaf(w, __uint_as_float(u.y & 0xffff0000u), a3);
    }
    a0 += c0; a1 += c1; a2 += c2; a3 += c3;
    uint2 o;
    o.x = packbf(a0, a1);
    o.y = packbf(a2, a3);
    *(uint2*)&z1[(((size_t)b * NN + i) * HID + l * 4) >> 1] = o;
}

// ---------------- gemm1: 128x128 tile, BK=32, 256 thr (proven R9/R10 shape) ----------------
template <int K, int N, bool OUT_BF16, int BK>
__global__ __launch_bounds__(256, 3) void gemm_mfma(const short* __restrict__ A,
                                                    const short* __restrict__ Bt,
                                                    const float* __restrict__ bias,
                                                    void* __restrict__ Cv) {
    __shared__ short lds[2][2][128 * BK];
    constexpr int NC = N / 128;
    constexpr int CH = (128 * BK * 2) / 4096;
    const int h = blockIdx.x;
    const int rtile = (h & 7) + 8 * (h / (8 * NC));
    const int ctile = (h >> 3) % NC;
    const int tid = threadIdx.x;
    const int lane = tid & 63;
    const int wid = tid >> 6;
    const int wr = wid >> 1, wc = wid & 1;
    const int lrow = lane & 15, lk = (lane >> 4) * 8;
    const int row0 = rtile * 128, col0 = ctile * 128;
    const short* gA = A + (size_t)row0 * K;
    const short* gB = Bt + (size_t)col0 * K;

    auto stage = [&](int buf, int kt) {
#pragma unroll
        for (int c = 0; c < CH; ++c) {
            int off = c * 4096 + tid * 16;
            int row = off / (2 * BK), kb = (off % (2 * BK)) >> 1;
            gload_lds16(gA + (size_t)row * K + kt + kb, (char*)&lds[buf][0][0] + off);
            gload_lds16(gB + (size_t)row * K + kt + kb, (char*)&lds[buf][1][0] + off);
        }
    };

    ffrag acc[4][4] = {};
    stage(0, 0);
    __syncthreads();
    const int NT = K / BK;
    int cur = 0;
    for (int kt = 0; kt < NT; ++kt) {
        if (kt + 1 < NT) stage(cur ^ 1, (kt + 1) * BK);
        const short* As = &lds[cur][0][0];
        const short* Bs = &lds[cur][1][0];
#pragma unroll
        for (int kk = 0; kk < BK / 32; ++kk) {
            bfrag a[4], b[4];
#pragma unroll
            for (int m = 0; m < 4; ++m)
                a[m] = *(const bfrag*)&As[(wr * 64 + m * 16 + lrow) * BK + kk * 32 + lk];
#pragma unroll
            for (int n = 0; n < 4; ++n)
                b[n] = *(const bfrag*)&Bs[(wc * 64 + n * 16 + lrow) * BK + kk * 32 + lk];
#pragma unroll
            for (int m = 0; m < 4; ++m)
#pragma unroll
                for (int n = 0; n < 4; ++n)
                    acc[m][n] = __builtin_amdgcn_mfma_f32_16x16x32_bf16(a[m], b[n], acc[m][n], 0, 0, 0);
        }
        __syncthreads();
        cur ^= 1;
    }

    const int orow = row0 + wr * 64 + (lane >> 4) * 4;
    const int ocol = col0 + wc * 64 + lrow;
#pragma unroll
    for (int n = 0; n < 4; ++n) {
        float bv = bias[ocol + n * 16];
#pragma unroll
        for (int m = 0; m < 4; ++m) {
#pragma unroll
            for (int r = 0; r < 4; ++r) {
                float v = fmaxf(acc[m][n][r] + bv, 0.f);
                size_t idx = (size_t)(orow + m * 16 + r) * N + (ocol + n * 16);
                if constexpr (OUT_BF16)
                    ((short*)Cv)[idx] = f2bf(v);
                else
                    ((float*)Cv)[idx] = v;
            }
        }
    }
}

// ---------------- gemm2: 128x256 tile, BK=32, 512 thr (8 waves 2x4) ----------------
template <int K>
__global__ __launch_bounds__(512, 4) void gemm_wide(const short* __restrict__ A,
                                                    const short* __restrict__ Bt,
                                                    const float* __restrict__ bias,
                                                    float* __restrict__ C) {
    constexpr int N = OUTF, BK = 32, BM = 128, BN = 256;
    __shared__ short lds[2][(BM + BN) * BK];
    const int h = blockIdx.x;
    const int rtile = (h & 7) + 8 * (h >> 5);
    const int ctile = (h >> 3) & 3;
    const int tid = threadIdx.x;
    const int lane = tid & 63, wid = tid >> 6;
    const int wr = wid >> 2, wc = wid & 3;
    const int lrow = lane & 15, lk = (lane >> 4) * 8;
    const short* gA = A + (size_t)(rtile * BM) * K;
    const short* gB = Bt + (size_t)(ctile * BN) * K;

    auto stage = [&](int buf, int kt) {
        {
            int off = tid * 16;
            int row = off >> 6, kb = (off & 63) >> 1;
            gload_lds16(gA + (size_t)row * K + kt + kb, (char*)&lds[buf][0] + off);
        }
#pragma unroll
        for (int c = 0; c < 2; ++c) {
            int off = c * 8192 + tid * 16;
            int row = off >> 6, kb = (off & 63) >> 1;
            gload_lds16(gB + (size_t)row * K + kt + kb, (char*)&lds[buf][BM * BK] + off);
        }
    };

    ffrag acc[4][4] = {};
    stage(0, 0);
    __syncthreads();
    const int NT = K / BK;
    int cur = 0;
    for (int kt = 0; kt < NT; ++kt) {
        if (kt + 1 < NT) stage(cur ^ 1, (kt + 1) * BK);
        const short* As = &lds[cur][0];
        const short* Bs = &lds[cur][BM * BK];
        bfrag a[4], b[4];
#pragma unroll
        for (int m = 0; m < 4; ++m)
            a[m] = *(const bfrag*)&As[(wr * 64 + m * 16 + lrow) * BK + lk];
#pragma unroll
        for (int n = 0; n < 4; ++n)
            b[n] = *(const bfrag*)&Bs[(wc * 64 + n * 16 + lrow) * BK + lk];
#pragma unroll
        for (int m = 0; m < 4; ++m)
#pragma unroll
            for (int n = 0; n < 4; ++n)
                acc[m][n] = __builtin_amdgcn_mfma_f32_16x16x32_bf16(a[m], b[n], acc[m][n], 0, 0, 0);
        __syncthreads();
        cur ^= 1;
    }

    const int orow = rtile * BM + wr * 64 + (lane >> 4) * 4;
    const int ocol = ctile * BN + wc * 64 + lrow;
#pragma unroll
    for (int n = 0; n < 4; ++n) {
        float bv = bias[ocol + n * 16];
#pragma unroll
        for (int m = 0; m < 4; ++m)
#pragma unroll
            for (int r = 0; r < 4; ++r) {
                float v = fmaxf(acc[m][n][r] + bv, 0.f);
                C[(size_t)(orow + m * 16 + r) * N + ocol + n * 16] = v;
            }
    }
}

extern "C" void kernel_launch(void* const* d_in, const int* in_sizes, int n_in,
                              void* d_out, int out_size, void* d_ws, size_t ws_size,
                              hipStream_t stream) {
    const float* nodes = (const float*)d_in[0];
    const int*   edges = (const int*)d_in[1];
    const float* W0    = (const float*)d_in[2];
    const float* b0    = (const float*)d_in[3];
    const float* W1    = (const float*)d_in[4];
    const float* b1    = (const float*)d_in[5];
    float* out = (float*)d_out;

    char* ws = (char*)d_ws;
    size_t off = 0;
    auto alloc = [&](size_t bytes) -> char* {
        char* p = ws + off;
        off = (off + bytes + 255) & ~(size_t)255;
        return p;
    };
    int*   cnt    = (int*)alloc((size_t)NB * NN * 4);
    int*   bucket = (int*)alloc((size_t)NB * NN * BCAP * 4);   // 4 MB
    short* W0t    = (short*)alloc((size_t)HID * OBS * 2);
    short* W1t    = (short*)alloc((size_t)OUTF * HID * 2);
    short* z0     = (short*)alloc((size_t)NB * NN * OBS * 2);  // 4 MB
    short* x1     = (short*)alloc((size_t)NB * NN * HID * 2);  // 8 MB
    short* z1     = (short*)alloc((size_t)NB * NN * HID * 2);  // 8 MB

    // 1: zero cnt (64 KB fill)
    hipMemsetAsync(cnt, 0, (size_t)NB * NN * 4, stream);
    // 2: edge bucket scatter + weight transposes
    k_bucket<<<(HID * OUTF) / 256, 256, 0, stream>>>(edges, W0, W1, cnt, bucket, W0t, W1t);
    // 3: z0 = S.nodes
    k_agg0<<<dim3(NN / 4, NB), 256, 0, stream>>>(nodes, cnt, bucket, (unsigned*)z0);
    // 4: x1 = relu(z0 @ W0 + b0)
    gemm_mfma<OBS, HID, true, 32><<<(NB * NN / 128) * (HID / 128), 256, 0, stream>>>(z0, W0t, b0, x1);
    // 5: z1 = S.x1
    k_agg1<<<dim3(NN / 4, NB), 256, 0, stream>>>(x1, cnt, bucket, (unsigned*)z1);
    // 6: out = relu(z1 @ W1 + b1)
    gemm_wide<HID><<<(NB * NN / 128) * (OUTF / 256), 512, 0, stream>>>(z1, W1t, b1, out);
}

// Round 13
// 67.904 us; speedup vs baseline: 1.9368x; 1.0232x over previous
//
#include <hip/hip_runtime.h>
#include <hip/hip_bf16.h>
#include <stdint.h>

#define NB   8
#define NN   2048
#define NE   16384
#define OBS  128
#define HID  256
#define OUTF 1024
#define BCAP 64   // per-node bucket capacity (mean deg 8, sigma 2.8)

using bfrag = __attribute__((ext_vector_type(8))) short;
using ffrag = __attribute__((ext_vector_type(4))) float;

__device__ __forceinline__ short f2bf(float f) {
    __hip_bfloat16 h = __float2bfloat16(f);
    return __builtin_bit_cast(short, h);
}
__device__ __forceinline__ unsigned packbf(float a, float b) {
    return ((unsigned)(unsigned short)f2bf(b) << 16) | (unsigned)(unsigned short)f2bf(a);
}
__device__ __forceinline__ void gload_lds16(const void* g, void* l) {
    __builtin_amdgcn_global_load_lds(
        (const __attribute__((address_space(1))) unsigned int*)g,
        (__attribute__((address_space(3))) unsigned int*)l, 16, 0, 0);
}

// ---------------- prep: W0^T, W1^T (f32->bf16, coalesced writes) + zero cnt ----------------
__global__ __launch_bounds__(256) void k_prep(const float* __restrict__ W0,
                                              const float* __restrict__ W1,
                                              short* __restrict__ W0t,
                                              short* __restrict__ W1t,
                                              int* __restrict__ cnt) {
    int idx = blockIdx.x * 256 + threadIdx.x;
    if (idx < HID * OUTF) {  // W1t [OUTF][HID]
        int n = idx / HID, k = idx - n * HID;
        W1t[idx] = f2bf(W1[k * OUTF + n]);
    }
    if (idx < OBS * HID) {   // W0t [HID][OBS]
        int n = idx / OBS, k = idx - n * OBS;
        W0t[idx] = f2bf(W0[k * HID + n]);
    }
    if (idx < NB * NN) cnt[idx] = 0;
}

// ---------------- bucket scatter: bucket[b][dst][cnt++] = src ----------------
__global__ __launch_bounds__(256) void k_bucket(const int* __restrict__ edges,
                                                int* __restrict__ cnt,
                                                int* __restrict__ bucket) {
    int idx = blockIdx.x * 256 + threadIdx.x;
    if (idx >= NB * NE) return;
    int b = idx / NE, e = idx - b * NE;
    int src = edges[(size_t)b * 2 * NE + e];
    int dst = edges[(size_t)b * 2 * NE + NE + e];
    int pos = atomicAdd(&cnt[b * NN + dst], 1);
    if (pos < BCAP) bucket[((size_t)b * NN + dst) * BCAP + pos] = src;
}

// ---------------- pre-GEMM aggregation z = S.x (wave per node, 4x MLP) ----------------
// z0 = S . nodes  (f32 in -> bf16 out, F=128; 2 f32/lane)
__global__ __launch_bounds__(256) void k_agg0(const float* __restrict__ nodes,
                                              const int* __restrict__ cnt,
                                              const int* __restrict__ bucket,
                                              unsigned* __restrict__ z0) {
    const int b = blockIdx.y, t = threadIdx.x;
    const int i = blockIdx.x * 4 + (t >> 6);
    const int l = t & 63;
    const int* cb = cnt + b * NN;
    const int deg = cb[i];
    const int degc = deg < BCAP ? deg : BCAP;
    const float di = rsqrtf((float)(deg + 1));
    int s_t = 0;
    float dv_t = 0.f;
    if (l < degc) {
        s_t = bucket[((size_t)b * NN + i) * BCAP + l];
        dv_t = rsqrtf((float)(cb[s_t] + 1));
    }
    const float* xb = nodes + (size_t)b * NN * OBS;
    float2 v = *(const float2*)&xb[(size_t)i * OBS + l * 2];
    float ax = di * di * v.x, ay = di * di * v.y;
    float bx = 0.f, by = 0.f;
    int e = 0;
    for (; e + 4 <= degc; e += 4) {
        int s0 = __shfl(s_t, e),     s1 = __shfl(s_t, e + 1);
        int s2 = __shfl(s_t, e + 2), s3 = __shfl(s_t, e + 3);
        float w0 = di * __shfl(dv_t, e),     w1 = di * __shfl(dv_t, e + 1);
        float w2 = di * __shfl(dv_t, e + 2), w3 = di * __shfl(dv_t, e + 3);
        float2 u0 = *(const float2*)&xb[(size_t)s0 * OBS + l * 2];
        float2 u1 = *(const float2*)&xb[(size_t)s1 * OBS + l * 2];
        float2 u2 = *(const float2*)&xb[(size_t)s2 * OBS + l * 2];
        float2 u3 = *(const float2*)&xb[(size_t)s3 * OBS + l * 2];
        ax = fmaf(w0, u0.x, ax); ay = fmaf(w0, u0.y, ay);
        bx = fmaf(w1, u1.x, bx); by = fmaf(w1, u1.y, by);
        ax = fmaf(w2, u2.x, ax); ay = fmaf(w2, u2.y, ay);
        bx = fmaf(w3, u3.x, bx); by = fmaf(w3, u3.y, by);
    }
    for (; e < degc; ++e) {
        int s = __shfl(s_t, e);
        float w = di * __shfl(dv_t, e);
        float2 u = *(const float2*)&xb[(size_t)s * OBS + l * 2];
        ax = fmaf(w, u.x, ax);
        ay = fmaf(w, u.y, ay);
    }
    ax += bx;
    ay += by;
    z0[(((size_t)b * NN + i) * OBS + l * 2) >> 1] = packbf(ax, ay);
}

// z1 = S . x1  (bf16 in -> bf16 out, F=256; 4 bf16/lane)
__global__ __launch_bounds__(256) void k_agg1(const short* __restrict__ x1,
                                              const int* __restrict__ cnt,
                                              const int* __restrict__ bucket,
                                              unsigned* __restrict__ z1) {
    const int b = blockIdx.y, t = threadIdx.x;
    const int i = blockIdx.x * 4 + (t >> 6);
    const int l = t & 63;
    const int* cb = cnt + b * NN;
    const int deg = cb[i];
    const int degc = deg < BCAP ? deg : BCAP;
    const float di = rsqrtf((float)(deg + 1));
    int s_t = 0;
    float dv_t = 0.f;
    if (l < degc) {
        s_t = bucket[((size_t)b * NN + i) * BCAP + l];
        dv_t = rsqrtf((float)(cb[s_t] + 1));
    }
    const short* xb = x1 + (size_t)b * NN * HID;
    uint2 raw = *(const uint2*)&xb[(size_t)i * HID + l * 4];
    const float di2 = di * di;
    float a0 = di2 * __uint_as_float(raw.x << 16);
    float a1 = di2 * __uint_as_float(raw.x & 0xffff0000u);
    float a2 = di2 * __uint_as_float(raw.y << 16);
    float a3 = di2 * __uint_as_float(raw.y & 0xffff0000u);
    float c0 = 0.f, c1 = 0.f, c2 = 0.f, c3 = 0.f;
    int e = 0;
    for (; e + 4 <= degc; e += 4) {
        int s0 = __shfl(s_t, e),     s1 = __shfl(s_t, e + 1);
        int s2 = __shfl(s_t, e + 2), s3 = __shfl(s_t, e + 3);
        float w0 = di * __shfl(dv_t, e),     w1 = di * __shfl(dv_t, e + 1);
        float w2 = di * __shfl(dv_t, e + 2), w3 = di * __shfl(dv_t, e + 3);
        uint2 u0 = *(const uint2*)&xb[(size_t)s0 * HID + l * 4];
        uint2 u1 = *(const uint2*)&xb[(size_t)s1 * HID + l * 4];
        uint2 u2 = *(const uint2*)&xb[(size_t)s2 * HID + l * 4];
        uint2 u3 = *(const uint2*)&xb[(size_t)s3 * HID + l * 4];
        a0 = fmaf(w0, __uint_as_float(u0.x << 16), a0);
        a1 = fmaf(w0, __uint_as_float(u0.x & 0xffff0000u), a1);
        a2 = fmaf(w0, __uint_as_float(u0.y << 16), a2);
        a3 = fmaf(w0, __uint_as_float(u0.y & 0xffff0000u), a3);
        c0 = fmaf(w1, __uint_as_float(u1.x << 16), c0);
        c1 = fmaf(w1, __uint_as_float(u1.x & 0xffff0000u), c1);
        c2 = fmaf(w1, __uint_as_float(u1.y << 16), c2);
        c3 = fmaf(w1, __uint_as_float(u1.y & 0xffff0000u), c3);
        a0 = fmaf(w2, __uint_as_float(u2.x << 16), a0);
        a1 = fmaf(w2, __uint_as_float(u2.x & 0xffff0000u), a1);
        a2 = fmaf(w2, __uint_as_float(u2.y << 16), a2);
        a3 = fmaf(w2, __uint_as_float(u2.y & 0xffff0000u), a3);
        c0 = fmaf(w3, __uint_as_float(u3.x << 16), c0);
        c1 = fmaf(w3, __uint_as_float(u3.x & 0xffff0000u), c1);
        c2 = fmaf(w3, __uint_as_float(u3.y << 16), c2);
        c3 = fmaf(w3, __uint_as_float(u3.y & 0xffff0000u), c3);
    }
    for (; e < degc; ++e) {
        int s = __shfl(s_t, e);
        float w = di * __shfl(dv_t, e);
        uint2 u = *(const uint2*)&xb[(size_t)s * HID + l * 4];
        a0 = fmaf(w, __uint_as_float(u.x << 16), a0);
        a1 = fmaf(w, __uint_as_float(u.x & 0xffff0000u), a1);
        a2 = fmaf(w, __uint_as_float(u.y << 16), a2);
        a3 = fmaf(w, __uint_as_float(u.y & 0xffff0000u), a3);
    }
    a0 += c0; a1 += c1; a2 += c2; a3 += c3;
    uint2 o;
    o.x = packbf(a0, a1);
    o.y = packbf(a2, a3);
    *(uint2*)&z1[(((size_t)b * NN + i) * HID + l * 4) >> 1] = o;
}

// ---------------- gemm1: 128x128 tile, BK=32, 256 thr ----------------
template <int K, int N, bool OUT_BF16, int BK>
__global__ __launch_bounds__(256, 3) void gemm_mfma(const short* __restrict__ A,
                                                    const short* __restrict__ Bt,
                                                    const float* __restrict__ bias,
                                                    void* __restrict__ Cv) {
    __shared__ short lds[2][2][128 * BK];
    constexpr int NC = N / 128;
    constexpr int CH = (128 * BK * 2) / 4096;
    const int h = blockIdx.x;
    const int rtile = (h & 7) + 8 * (h / (8 * NC));
    const int ctile = (h >> 3) % NC;
    const int tid = threadIdx.x;
    const int lane = tid & 63;
    const int wid = tid >> 6;
    const int wr = wid >> 1, wc = wid & 1;
    const int lrow = lane & 15, lk = (lane >> 4) * 8;
    const int row0 = rtile * 128, col0 = ctile * 128;
    const short* gA = A + (size_t)row0 * K;
    const short* gB = Bt + (size_t)col0 * K;

    auto stage = [&](int buf, int kt) {
#pragma unroll
        for (int c = 0; c < CH; ++c) {
            int off = c * 4096 + tid * 16;
            int row = off / (2 * BK), kb = (off % (2 * BK)) >> 1;
            gload_lds16(gA + (size_t)row * K + kt + kb, (char*)&lds[buf][0][0] + off);
            gload_lds16(gB + (size_t)row * K + kt + kb, (char*)&lds[buf][1][0] + off);
        }
    };

    ffrag acc[4][4] = {};
    stage(0, 0);
    __syncthreads();
    const int NT = K / BK;
    int cur = 0;
    for (int kt = 0; kt < NT; ++kt) {
        if (kt + 1 < NT) stage(cur ^ 1, (kt + 1) * BK);
        const short* As = &lds[cur][0][0];
        const short* Bs = &lds[cur][1][0];
#pragma unroll
        for (int kk = 0; kk < BK / 32; ++kk) {
            bfrag a[4], b[4];
#pragma unroll
            for (int m = 0; m < 4; ++m)
                a[m] = *(const bfrag*)&As[(wr * 64 + m * 16 + lrow) * BK + kk * 32 + lk];
#pragma unroll
            for (int n = 0; n < 4; ++n)
                b[n] = *(const bfrag*)&Bs[(wc * 64 + n * 16 + lrow) * BK + kk * 32 + lk];
#pragma unroll
            for (int m = 0; m < 4; ++m)
#pragma unroll
                for (int n = 0; n < 4; ++n)
                    acc[m][n] = __builtin_amdgcn_mfma_f32_16x16x32_bf16(a[m], b[n], acc[m][n], 0, 0, 0);
        }
        __syncthreads();
        cur ^= 1;
    }

    const int orow = row0 + wr * 64 + (lane >> 4) * 4;
    const int ocol = col0 + wc * 64 + lrow;
#pragma unroll
    for (int n = 0; n < 4; ++n) {
        float bv = bias[ocol + n * 16];
#pragma unroll
        for (int m = 0; m < 4; ++m) {
#pragma unroll
            for (int r = 0; r < 4; ++r) {
                float v = fmaxf(acc[m][n][r] + bv, 0.f);
                size_t idx = (size_t)(orow + m * 16 + r) * N + (ocol + n * 16);
                if constexpr (OUT_BF16)
                    ((short*)Cv)[idx] = f2bf(v);
                else
                    ((float*)Cv)[idx] = v;
            }
        }
    }
}

// ---------------- gemm2: 128x256 tile, BK=32, 512 thr (8 waves 2x4) ----------------
template <int K>
__global__ __launch_bounds__(512, 4) void gemm_wide(const short* __restrict__ A,
                                                    const short* __restrict__ Bt,
                                                    const float* __restrict__ bias,
                                                    float* __restrict__ C) {
    constexpr int N = OUTF, BK = 32, BM = 128, BN = 256;
    __shared__ short lds[2][(BM + BN) * BK];
    const int h = blockIdx.x;
    const int rtile = (h & 7) + 8 * (h >> 5);
    const int ctile = (h >> 3) & 3;
    const int tid = threadIdx.x;
    const int lane = tid & 63, wid = tid >> 6;
    const int wr = wid >> 2, wc = wid & 3;
    const int lrow = lane & 15, lk = (lane >> 4) * 8;
    const short* gA = A + (size_t)(rtile * BM) * K;
    const short* gB = Bt + (size_t)(ctile * BN) * K;

    auto stage = [&](int buf, int kt) {
        {
            int off = tid * 16;
            int row = off >> 6, kb = (off & 63) >> 1;
            gload_lds16(gA + (size_t)row * K + kt + kb, (char*)&lds[buf][0] + off);
        }
#pragma unroll
        for (int c = 0; c < 2; ++c) {
            int off = c * 8192 + tid * 16;
            int row = off >> 6, kb = (off & 63) >> 1;
            gload_lds16(gB + (size_t)row * K + kt + kb, (char*)&lds[buf][BM * BK] + off);
        }
    };

    ffrag acc[4][4] = {};
    stage(0, 0);
    __syncthreads();
    const int NT = K / BK;
    int cur = 0;
    for (int kt = 0; kt < NT; ++kt) {
        if (kt + 1 < NT) stage(cur ^ 1, (kt + 1) * BK);
        const short* As = &lds[cur][0];
        const short* Bs = &lds[cur][BM * BK];
        bfrag a[4], b[4];
#pragma unroll
        for (int m = 0; m < 4; ++m)
            a[m] = *(const bfrag*)&As[(wr * 64 + m * 16 + lrow) * BK + lk];
#pragma unroll
        for (int n = 0; n < 4; ++n)
            b[n] = *(const bfrag*)&Bs[(wc * 64 + n * 16 + lrow) * BK + lk];
#pragma unroll
        for (int m = 0; m < 4; ++m)
#pragma unroll
            for (int n = 0; n < 4; ++n)
                acc[m][n] = __builtin_amdgcn_mfma_f32_16x16x32_bf16(a[m], b[n], acc[m][n], 0, 0, 0);
        __syncthreads();
        cur ^= 1;
    }

    const int orow = rtile * BM + wr * 64 + (lane >> 4) * 4;
    const int ocol = ctile * BN + wc * 64 + lrow;
#pragma unroll
    for (int n = 0; n < 4; ++n) {
        float bv = bias[ocol + n * 16];
#pragma unroll
        for (int m = 0; m < 4; ++m)
#pragma unroll
            for (int r = 0; r < 4; ++r) {
                float v = fmaxf(acc[m][n][r] + bv, 0.f);
                C[(size_t)(orow + m * 16 + r) * N + ocol + n * 16] = v;
            }
    }
}

extern "C" void kernel_launch(void* const* d_in, const int* in_sizes, int n_in,
                              void* d_out, int out_size, void* d_ws, size_t ws_size,
                              hipStream_t stream) {
    const float* nodes = (const float*)d_in[0];
    const int*   edges = (const int*)d_in[1];
    const float* W0    = (const float*)d_in[2];
    const float* b0    = (const float*)d_in[3];
    const float* W1    = (const float*)d_in[4];
    const float* b1    = (const float*)d_in[5];
    float* out = (float*)d_out;

    char* ws = (char*)d_ws;
    size_t off = 0;
    auto alloc = [&](size_t bytes) -> char* {
        char* p = ws + off;
        off = (off + bytes + 255) & ~(size_t)255;
        return p;
    };
    int*   cnt    = (int*)alloc((size_t)NB * NN * 4);
    int*   bucket = (int*)alloc((size_t)NB * NN * BCAP * 4);   // 4 MB
    short* W0t    = (short*)alloc((size_t)HID * OBS * 2);
    short* W1t    = (short*)alloc((size_t)OUTF * HID * 2);
    short* z0     = (short*)alloc((size_t)NB * NN * OBS * 2);  // 4 MB
    short* x1     = (short*)alloc((size_t)NB * NN * HID * 2);  // 8 MB
    short* z1     = (short*)alloc((size_t)NB * NN * HID * 2);  // 8 MB

    k_prep<<<(HID * OUTF + 255) / 256, 256, 0, stream>>>(W0, W1, W0t, W1t, cnt);
    k_bucket<<<(NB * NE + 255) / 256, 256, 0, stream>>>(edges, cnt, bucket);
    k_agg0<<<dim3(NN / 4, NB), 256, 0, stream>>>(nodes, cnt, bucket, (unsigned*)z0);
    gemm_mfma<OBS, HID, true, 32><<<(NB * NN / 128) * (HID / 128), 256, 0, stream>>>(z0, W0t, b0, x1);
    k_agg1<<<dim3(NN / 4, NB), 256, 0, stream>>>(x1, cnt, bucket, (unsigned*)z1);
    gemm_wide<HID><<<(NB * NN / 128) * (OUTF / 256), 512, 0, stream>>>(z1, W1t, b1, out);
}